// Round 2
// 134.522 us; speedup vs baseline: 1.0352x; 1.0352x over previous
//
#include <hip/hip_runtime.h>
#include <hip/hip_bf16.h>

// Problem constants (fixed by setup_inputs)
constexpr int B = 512;   // batch
constexpr int D = 4096;  // D_vis
constexpr int E = 1024;  // embed dim
constexpr int N = 512;   // negatives
constexpr int KS = 4;    // GEMM K-split factor
constexpr int KC = D / KS;      // 1024 K per split
constexpr int NSTEP = KC / 32;  // 32 k-steps per wave
constexpr int ES = 8;    // scores E-split factor
constexpr int EC = E / ES;      // 128 e per scores block
constexpr int DEPTH = 4;        // GEMM pipeline depth (LDS buffers)

typedef __attribute__((ext_vector_type(8))) short bf16x8;   // 8 bf16 = 4 VGPRs
typedef __attribute__((ext_vector_type(4))) float f32x4;
typedef float v2f __attribute__((ext_vector_type(2)));

typedef __attribute__((address_space(3))) void lds_void;
typedef const __attribute__((address_space(1))) void gbl_void;

__device__ __forceinline__ unsigned short f2bf(float f) {
    __hip_bfloat16 h = __float2bfloat16(f);   // RTNE
    return *reinterpret_cast<unsigned short*>(&h);
}

// ---------------------------------------------------------------------------
// Kernel 0: f32 -> bf16 convert for BOTH vf and W in one dispatch.
// ---------------------------------------------------------------------------
__global__ __launch_bounds__(256) void cvt_all(
    const float* __restrict__ vf, const float* __restrict__ W,
    unsigned short* __restrict__ vfB, unsigned short* __restrict__ WB)
{
    const int bid = blockIdx.x;
    const float* src;
    unsigned short* dst;
    int i;
    if (bid < 1024) { src = vf; dst = vfB; i = (bid * 256 + threadIdx.x) * 8; }
    else           { src = W;  dst = WB;  i = ((bid - 1024) * 256 + threadIdx.x) * 8; }
    float4 v0 = *(const float4*)(src + i);
    float4 v1 = *(const float4*)(src + i + 4);
    bf16x8 o;
    o[0] = (short)f2bf(v0.x); o[1] = (short)f2bf(v0.y);
    o[2] = (short)f2bf(v0.z); o[3] = (short)f2bf(v0.w);
    o[4] = (short)f2bf(v1.x); o[5] = (short)f2bf(v1.y);
    o[6] = (short)f2bf(v1.z); o[7] = (short)f2bf(v1.w);
    *(bf16x8*)(dst + i) = o;
}

// ---------------------------------------------------------------------------
// Kernel 1: K-split GEMM, one wave per block, 64(m) x 64(n) tile, KS=4.
// grid (16,8,4) = 512 blocks = 2 blocks/CU.
//  (a) XCD-chunked block swizzle: hardware round-robins linear block id % 8
//      across XCDs; remap so XCD c owns logical ids [64c, 64c+64) = an
//      8(y) x 8(x-half) sub-grid at fixed (ks, x-half). Unique working set
//      per XCD = 1MB A-rows + 1MB B-rows = 2MB < 4MiB L2 (was ~5MB, thrash).
//  (b) Pipeline depth 4 (32KB LDS/block): steady-state vmcnt(24) keeps
//      3 buffers in flight (~3 iters ~ 350cyc) to cover L2-hit latency.
//      Tail peeled with vmcnt(24/16/8/0).
// LDS layout: tile stored as 16B chunks, chunk(row, qs) at (row*4+qs)*16,
// holding global (row, q) where q = qs ^ (row&3) ^ ((row>>2)&3).
// -> staging lane L (chunk c*64+L) reads row c*16+(L>>2), q = (L&3)^((L>>2)&3)^((L>>4)&3)
// -> frag ds_read_b128 at row i*16+r16, q=quad is 2-way bank aliased (free, m136).
// A-frag: A[m=lane&15][k=quad*8+j]; B-frag: B[k=quad*8+j][n=lane&15].
// C/D: col=lane&15, row=quad*4+reg  [verified rounds 2-4 of prior session]
// ---------------------------------------------------------------------------
__global__ __launch_bounds__(64) void gemm_lds(
    const unsigned short* __restrict__ vf,    // [B, D] bf16 bits
    const unsigned short* __restrict__ W,     // [E, D] bf16 bits
    float* __restrict__ part)                 // [KS, B, E] f32
{
    __shared__ unsigned short sA[DEPTH][2048];    // DEPTH bufs x 64x32 bf16 (4 KB each)
    __shared__ unsigned short sB[DEPTH][2048];

    const int L  = threadIdx.x;

    // ---- XCD-chunked swizzle: linear id -> logical tile ----
    // id = bx + 16*by + 128*bz; HW XCD ~ id%8. logical l = (id%8)*64 + id/8
    // decode: ks = l>>7, x = ((l>>6)&1)*8 + (l&7), y = (l>>3)&7.
    // Per XCD: ks and x-half constant; y,x-low sweep 8x8 -> 2MB unique.
    const int id = blockIdx.x + 16 * blockIdx.y + 128 * blockIdx.z;
    const int l  = (id & 7) * 64 + (id >> 3);
    const int ks = l >> 7;
    const int n0 = ((((l >> 6) & 1) << 3) | (l & 7)) * 64;
    const int m0 = ((l >> 3) & 7) * 64;

    // ---- staging addresses: per call c (0..3), lane L covers chunk c*64+L ----
    const int subrow = L >> 2;                                  // 0..15
    const int qstg = (L & 3) ^ ((L >> 2) & 3) ^ ((L >> 4) & 3); // swizzled k-group
    const int kbeg = ks * KC;
    const unsigned short* aSrc[4];
    const unsigned short* bSrc[4];
    #pragma unroll
    for (int c = 0; c < 4; ++c) {
        aSrc[c] = vf + (size_t)(m0 + c * 16 + subrow) * D + kbeg + qstg * 8;
        bSrc[c] = W  + (size_t)(n0 + c * 16 + subrow) * D + kbeg + qstg * 8;
    }

    // ---- fragment read offsets ----
    const int r16 = L & 15;
    const int quad = L >> 4;
    const int swz = quad ^ (r16 & 3) ^ ((r16 >> 2) & 3);
    const int aoff = r16 * 64 + swz * 16;   // byte offset within a buffer

    f32x4 acc[4][4] = {};

    auto issue = [&](int step, int buf) {
        const size_t koff = (size_t)step * 32;   // elements
        #pragma unroll
        for (int c = 0; c < 4; ++c) {
            __builtin_amdgcn_global_load_lds(
                (gbl_void*)(aSrc[c] + koff),
                (lds_void*)((char*)&sA[buf][0] + c * 1024), 16, 0, 0);
            __builtin_amdgcn_global_load_lds(
                (gbl_void*)(bSrc[c] + koff),
                (lds_void*)((char*)&sB[buf][0] + c * 1024), 16, 0, 0);
        }
    };

    issue(0, 0);
    issue(1, 1);
    issue(2, 2);
    issue(3, 3);

    // waitcnt imm encoding (gfx9-lineage): lgkm/exp free; vmcnt split [3:0]+[15:14]:
    //   N=24 -> 0x4F78, N=16 -> 0x4F70, N=8 -> 0x0F78, N=0 -> 0x0F70
    #define GSTEP(S, WC, ISS)                                                  \
    {                                                                          \
        const int buf_ = (S) & 3;                                              \
        __builtin_amdgcn_s_waitcnt(WC);                                        \
        bf16x8 af[4], bg[4];                                                   \
        _Pragma("unroll")                                                      \
        for (int i = 0; i < 4; ++i)                                            \
            af[i] = *(const bf16x8*)((const char*)&sA[buf_][0] + i * 1024 + aoff); \
        _Pragma("unroll")                                                      \
        for (int j = 0; j < 4; ++j)                                            \
            bg[j] = *(const bf16x8*)((const char*)&sB[buf_][0] + j * 1024 + aoff); \
        _Pragma("unroll")                                                      \
        for (int i = 0; i < 4; ++i)                                            \
            _Pragma("unroll")                                                  \
            for (int j = 0; j < 4; ++j)                                        \
                acc[i][j] = __builtin_amdgcn_mfma_f32_16x16x32_bf16(           \
                    af[i], bg[j], acc[i][j], 0, 0, 0);                         \
        if (ISS) issue((S) + DEPTH, buf_);                                     \
    }

    #pragma unroll 1
    for (int s = 0; s < NSTEP - DEPTH; ++s)
        GSTEP(s, 0x4F78, true);              // steady state: vmcnt(24)
    GSTEP(NSTEP - 4, 0x4F78, false);         // vmcnt(24)
    GSTEP(NSTEP - 3, 0x4F70, false);         // vmcnt(16)
    GSTEP(NSTEP - 2, 0x0F78, false);         // vmcnt(8)
    GSTEP(NSTEP - 1, 0x0F70, false);         // vmcnt(0)
    #undef GSTEP

    float* po = part + (size_t)ks * B * E;
    #pragma unroll
    for (int j = 0; j < 4; ++j) {
        const int col = n0 + j * 16 + r16;
        #pragma unroll
        for (int i = 0; i < 4; ++i) {
            const int row = m0 + i * 16 + quad * 4;
            #pragma unroll
            for (int r = 0; r < 4; ++r)
                po[(size_t)(row + r) * E + col] = acc[i][j][r];
        }
    }
}

// ---------------------------------------------------------------------------
// Kernel 2: emb[b][e] = sum_ks part[ks][b][e] + bias[e]
// ---------------------------------------------------------------------------
__global__ __launch_bounds__(256) void reduce_emb(
    const float* __restrict__ part, const float* __restrict__ bias,
    float* __restrict__ emb)
{
    const int idx = (blockIdx.x * 256 + threadIdx.x) * 4;
    const int col = idx & (E - 1);
    float4 s = *(const float4*)(bias + col);
    #pragma unroll
    for (int ks = 0; ks < KS; ++ks) {
        float4 p = *(const float4*)(part + (size_t)ks * B * E + idx);
        s.x += p.x; s.y += p.y; s.z += p.z; s.w += p.w;
    }
    *(float4*)(emb + idx) = s;
}

// ---------------------------------------------------------------------------
// Kernel 3: neg-score partials.
// grid (8,8,8) = 512 blocks = 2 blocks/CU = 8 waves/CU.
// Tile 64(b) x 64(n), 4x4 v2f accs/thread, one EC=128 chunk per block.
// ---------------------------------------------------------------------------
__global__ __launch_bounds__(256, 2) void scores_part(
    const float* __restrict__ emb,    // [B, E] f32
    const float* __restrict__ n_lfs,  // [N, E] f32
    float* __restrict__ pn)           // [ES, B, N] f32
{
    constexpr int LDW = EC + 2;  // 130
    __shared__ float eS[64 * LDW];
    __shared__ float nS[64 * LDW];

    const int t  = threadIdx.x;
    const int n0 = blockIdx.x * 64;
    const int b0 = blockIdx.y * 64;
    const int e0 = blockIdx.z * EC;

    {
        const int row = t >> 2;            // 0..63
        const int cb  = (t & 3) * 32;      // 0,32,64,96
        const float* ep = emb   + (size_t)(b0 + row) * E + e0 + cb;
        const float* np = n_lfs + (size_t)(n0 + row) * E + e0 + cb;
        float* ed = &eS[row * LDW + cb];
        float* nd = &nS[row * LDW + cb];
        #pragma unroll
        for (int q = 0; q < 8; ++q) {
            float4 v = *(const float4*)(ep + q * 4);
            float4 w = *(const float4*)(np + q * 4);
            *(v2f*)(ed + q * 4)     = (v2f){v.x, v.y};
            *(v2f*)(ed + q * 4 + 2) = (v2f){v.z, v.w};
            *(v2f*)(nd + q * 4)     = (v2f){w.x, w.y};
            *(v2f*)(nd + q * 4 + 2) = (v2f){w.z, w.w};
        }
    }
    __syncthreads();

    const int ty = t >> 4;   // 0..15 -> b rows ty+16r
    const int tx = t & 15;   // 0..15 -> n rows tx+16c

    const v2f z = {0.f, 0.f};
    v2f acc[4][4] = {{z,z,z,z},{z,z,z,z},{z,z,z,z},{z,z,z,z}};

    #pragma unroll 4
    for (int e = 0; e < EC; e += 2) {
        v2f a[4], c[4];
        #pragma unroll
        for (int r = 0; r < 4; ++r)
            a[r] = *(const v2f*)&eS[(ty + 16 * r) * LDW + e];
        #pragma unroll
        for (int q = 0; q < 4; ++q)
            c[q] = *(const v2f*)&nS[(tx + 16 * q) * LDW + e];
        #pragma unroll
        for (int r = 0; r < 4; ++r)
            #pragma unroll
            for (int q = 0; q < 4; ++q) {
                v2f d = c[q] - a[r];
                d = __builtin_elementwise_max(d, z);
                acc[r][q] = __builtin_elementwise_fma(d, d, acc[r][q]);
            }
    }

    float* po = pn + (size_t)blockIdx.z * B * N;
    #pragma unroll
    for (int r = 0; r < 4; ++r) {
        const size_t ob = (size_t)(b0 + ty + 16 * r) * N;
        #pragma unroll
        for (int q = 0; q < 4; ++q)
            po[ob + n0 + tx + 16 * q] = acc[r][q].x + acc[r][q].y;
    }
}

// ---------------------------------------------------------------------------
// Kernel 4: final scores (negatives reduce + positive scores).
// ---------------------------------------------------------------------------
__global__ __launch_bounds__(256) void scores_final(
    const float* __restrict__ pn,     // [ES, B, N]
    const float* __restrict__ emb,    // [B, E]
    const float* __restrict__ p_lfs,  // [B, E]
    float* __restrict__ out)          // [B, 1+N]
{
    const int t = threadIdx.x;
    if (blockIdx.x < 1024) {
        const int i = blockIdx.x * 256 + t;       // 0..B*N-1
        const int b = i >> 9;                     // /N
        const int n = i & (N - 1);
        float s = 0.f;
        #pragma unroll
        for (int z = 0; z < ES; ++z)
            s += pn[(size_t)z * B * N + i];
        out[(size_t)b * 513 + 1 + n] = -sqrtf(s);
        return;
    }
    const int b0 = (blockIdx.x - 1024) * 32;
    const int r = t >> 3;        // 0..31
    const int g = t & 7;         // 8 threads per row
    const float* pr = p_lfs + (size_t)(b0 + r) * E;
    const float* er = emb   + (size_t)(b0 + r) * E;
    float acc = 0.f;
    for (int e = g * 4; e < E; e += 32) {
        float4 p = *(const float4*)(pr + e);
        float4 v = *(const float4*)(er + e);
        float d;
        d = p.x - v.x; d = fmaxf(d, 0.f); acc = fmaf(d, d, acc);
        d = p.y - v.y; d = fmaxf(d, 0.f); acc = fmaf(d, d, acc);
        d = p.z - v.z; d = fmaxf(d, 0.f); acc = fmaf(d, d, acc);
        d = p.w - v.w; d = fmaxf(d, 0.f); acc = fmaf(d, d, acc);
    }
    #pragma unroll
    for (int off = 4; off; off >>= 1) acc += __shfl_down(acc, off, 8);
    if (g == 0) out[(size_t)(b0 + r) * 513] = -sqrtf(acc);
}

extern "C" void kernel_launch(void* const* d_in, const int* in_sizes, int n_in,
                              void* d_out, int out_size, void* d_ws, size_t ws_size,
                              hipStream_t stream) {
    const float* vf    = (const float*)d_in[0];  // [512,4096] f32
    const float* p_lfs = (const float*)d_in[1];  // [512,1024] f32
    const float* n_lfs = (const float*)d_in[2];  // [512,1024] f32
    const float* W     = (const float*)d_in[3];  // [1024,4096] f32
    const float* bias  = (const float*)d_in[4];  // [1024] f32
    float* out = (float*)d_out;                  // [512,513] f32

    // ws layout (22 MB peak):
    //   [0,  8MB): pg   f32 [KS=4,512,1024]  (dead after reduce_emb)
    //   [0,  8MB): pn   f32 [ES=8,512,512]   (overlays dead pg)
    //   [8, 12MB): vfB  bf16 [512,4096]
    //   [12,20MB): WB   bf16 [1024,4096]
    //   [20,22MB): emb  f32 [512,1024]
    char* ws = (char*)d_ws;
    float*          pg  = (float*)ws;
    float*          pn  = (float*)ws;
    unsigned short* vfB = (unsigned short*)(ws + ((size_t)8 << 20));
    unsigned short* WB  = (unsigned short*)(ws + ((size_t)12 << 20));
    float*          emb = (float*)(ws + ((size_t)20 << 20));

    cvt_all<<<3072, 256, 0, stream>>>(vf, W, vfB, WB);

    dim3 g1(E / 64, B / 64, KS);   // (16, 8, 4) = 512 one-wave blocks
    gemm_lds<<<g1, 64, 0, stream>>>(vfB, WB, pg);

    reduce_emb<<<(B * E) / 1024, 256, 0, stream>>>(pg, bias, emb);

    dim3 g3(N / 64, B / 64, ES);   // (8, 8, 8) = 512 blocks
    scores_part<<<g3, 256, 0, stream>>>(emb, n_lfs, pn);

    scores_final<<<1024 + B / 32, 256, 0, stream>>>(pn, emb, p_lfs, out);
}

// Round 3
// 132.767 us; speedup vs baseline: 1.0488x; 1.0132x over previous
//
#include <hip/hip_runtime.h>
#include <hip/hip_bf16.h>

// Problem constants (fixed by setup_inputs)
constexpr int B = 512;   // batch
constexpr int D = 4096;  // D_vis
constexpr int E = 1024;  // embed dim
constexpr int N = 512;   // negatives
constexpr int KS = 8;    // GEMM K-split factor (r3: 4 -> 8 for TLP: 4 waves/CU)
constexpr int KC = D / KS;      // 512 K per split
constexpr int NSTEP = KC / 32;  // 16 k-steps per wave
constexpr int ES = 8;    // scores E-split factor
constexpr int EC = E / ES;      // 128 e per scores block
constexpr int DEPTH = 4;        // GEMM pipeline depth (LDS buffers)

typedef __attribute__((ext_vector_type(8))) short bf16x8;   // 8 bf16 = 4 VGPRs
typedef __attribute__((ext_vector_type(4))) float f32x4;
typedef float v2f __attribute__((ext_vector_type(2)));

typedef __attribute__((address_space(3))) void lds_void;
typedef const __attribute__((address_space(1))) void gbl_void;

__device__ __forceinline__ unsigned short f2bf(float f) {
    __hip_bfloat16 h = __float2bfloat16(f);   // RTNE
    return *reinterpret_cast<unsigned short*>(&h);
}

// ---------------------------------------------------------------------------
// Kernel 0: f32 -> bf16 convert for BOTH vf and W in one dispatch.
// ---------------------------------------------------------------------------
__global__ __launch_bounds__(256) void cvt_all(
    const float* __restrict__ vf, const float* __restrict__ W,
    unsigned short* __restrict__ vfB, unsigned short* __restrict__ WB)
{
    const int bid = blockIdx.x;
    const float* src;
    unsigned short* dst;
    int i;
    if (bid < 1024) { src = vf; dst = vfB; i = (bid * 256 + threadIdx.x) * 8; }
    else           { src = W;  dst = WB;  i = ((bid - 1024) * 256 + threadIdx.x) * 8; }
    float4 v0 = *(const float4*)(src + i);
    float4 v1 = *(const float4*)(src + i + 4);
    bf16x8 o;
    o[0] = (short)f2bf(v0.x); o[1] = (short)f2bf(v0.y);
    o[2] = (short)f2bf(v0.z); o[3] = (short)f2bf(v0.w);
    o[4] = (short)f2bf(v1.x); o[5] = (short)f2bf(v1.y);
    o[6] = (short)f2bf(v1.z); o[7] = (short)f2bf(v1.w);
    *(bf16x8*)(dst + i) = o;
}

// ---------------------------------------------------------------------------
// Kernel 1: K-split GEMM, one wave per block, 64(m) x 64(n) tile, KS=8.
// grid (16,8,8) = 1024 blocks = 4 blocks/CU = 4 waves/CU (1/SIMD).
// r3 theory: gemm was latency-bound at 2 waves/CU (0.5/SIMD) -- per-wave
// pipelining (depth 4, r2) did NOT move it, so the exposed stall must be
// covered by TLP instead. KS=8 doubles resident waves; each SIMD now has
// a wave to run while another waits on vmcnt.
//  (a) XCD-chunked block swizzle: HW round-robins linear id % 8 across XCDs;
//      remap so XCD c owns logical l in [128c, 128c+128) = fixed ks,
//      all 8 m-blocks x 16 n-blocks. Working set/XCD = 0.5MB A + 1MB B < 4MiB L2.
//  (b) Pipeline depth 4 (32KB LDS/block), steady-state vmcnt(24),
//      tail peeled with vmcnt(24/16/8/0).
// LDS layout: tile stored as 16B chunks, chunk(row, qs) at (row*4+qs)*16,
// holding global (row, q) where q = qs ^ (row&3) ^ ((row>>2)&3).
// -> staging lane L (chunk c*64+L) reads row c*16+(L>>2), q = (L&3)^((L>>2)&3)^((L>>4)&3)
// -> frag ds_read_b128 at row i*16+r16, q=quad is 2-way bank aliased (free, m136).
// A-frag: A[m=lane&15][k=quad*8+j]; B-frag: B[k=quad*8+j][n=lane&15].
// C/D: col=lane&15, row=quad*4+reg  [verified rounds 2-4 of prior session]
// ---------------------------------------------------------------------------
__global__ __launch_bounds__(64) void gemm_lds(
    const unsigned short* __restrict__ vf,    // [B, D] bf16 bits
    const unsigned short* __restrict__ W,     // [E, D] bf16 bits
    float* __restrict__ part)                 // [KS, B, E] f32
{
    __shared__ unsigned short sA[DEPTH][2048];    // DEPTH bufs x 64x32 bf16 (4 KB each)
    __shared__ unsigned short sB[DEPTH][2048];

    const int L  = threadIdx.x;

    // ---- XCD-chunked swizzle: linear id -> logical tile ----
    // id = bx + 16*by + 128*bz in [0,1024); HW XCD ~ id%8.
    // logical l = (id%8)*128 + id/8; decode: ks = l>>7 (fixed per XCD),
    // n-block = l&15, m-block = (l>>4)&7.
    const int id = blockIdx.x + 16 * blockIdx.y + 128 * blockIdx.z;
    const int l  = (id & 7) * 128 + (id >> 3);
    const int ks = l >> 7;
    const int n0 = (l & 15) * 64;
    const int m0 = ((l >> 4) & 7) * 64;

    // ---- staging addresses: per call c (0..3), lane L covers chunk c*64+L ----
    const int subrow = L >> 2;                                  // 0..15
    const int qstg = (L & 3) ^ ((L >> 2) & 3) ^ ((L >> 4) & 3); // swizzled k-group
    const int kbeg = ks * KC;
    const unsigned short* aSrc[4];
    const unsigned short* bSrc[4];
    #pragma unroll
    for (int c = 0; c < 4; ++c) {
        aSrc[c] = vf + (size_t)(m0 + c * 16 + subrow) * D + kbeg + qstg * 8;
        bSrc[c] = W  + (size_t)(n0 + c * 16 + subrow) * D + kbeg + qstg * 8;
    }

    // ---- fragment read offsets ----
    const int r16 = L & 15;
    const int quad = L >> 4;
    const int swz = quad ^ (r16 & 3) ^ ((r16 >> 2) & 3);
    const int aoff = r16 * 64 + swz * 16;   // byte offset within a buffer

    f32x4 acc[4][4] = {};

    auto issue = [&](int step, int buf) {
        const size_t koff = (size_t)step * 32;   // elements
        #pragma unroll
        for (int c = 0; c < 4; ++c) {
            __builtin_amdgcn_global_load_lds(
                (gbl_void*)(aSrc[c] + koff),
                (lds_void*)((char*)&sA[buf][0] + c * 1024), 16, 0, 0);
            __builtin_amdgcn_global_load_lds(
                (gbl_void*)(bSrc[c] + koff),
                (lds_void*)((char*)&sB[buf][0] + c * 1024), 16, 0, 0);
        }
    };

    issue(0, 0);
    issue(1, 1);
    issue(2, 2);
    issue(3, 3);

    // waitcnt imm encoding (gfx9-lineage): lgkm/exp free; vmcnt split [3:0]+[15:14]:
    //   N=24 -> 0x4F78, N=16 -> 0x4F70, N=8 -> 0x0F78, N=0 -> 0x0F70
    #define GSTEP(S, WC, ISS)                                                  \
    {                                                                          \
        const int buf_ = (S) & 3;                                              \
        __builtin_amdgcn_s_waitcnt(WC);                                        \
        bf16x8 af[4], bg[4];                                                   \
        _Pragma("unroll")                                                      \
        for (int i = 0; i < 4; ++i)                                            \
            af[i] = *(const bf16x8*)((const char*)&sA[buf_][0] + i * 1024 + aoff); \
        _Pragma("unroll")                                                      \
        for (int j = 0; j < 4; ++j)                                            \
            bg[j] = *(const bf16x8*)((const char*)&sB[buf_][0] + j * 1024 + aoff); \
        _Pragma("unroll")                                                      \
        for (int i = 0; i < 4; ++i)                                            \
            _Pragma("unroll")                                                  \
            for (int j = 0; j < 4; ++j)                                        \
                acc[i][j] = __builtin_amdgcn_mfma_f32_16x16x32_bf16(           \
                    af[i], bg[j], acc[i][j], 0, 0, 0);                         \
        if (ISS) issue((S) + DEPTH, buf_);                                     \
    }

    #pragma unroll 1
    for (int s = 0; s < NSTEP - DEPTH; ++s)
        GSTEP(s, 0x4F78, true);              // steady state: vmcnt(24)
    GSTEP(NSTEP - 4, 0x4F78, false);         // vmcnt(24)
    GSTEP(NSTEP - 3, 0x4F70, false);         // vmcnt(16)
    GSTEP(NSTEP - 2, 0x0F78, false);         // vmcnt(8)
    GSTEP(NSTEP - 1, 0x0F70, false);         // vmcnt(0)
    #undef GSTEP

    float* po = part + (size_t)ks * B * E;
    #pragma unroll
    for (int j = 0; j < 4; ++j) {
        const int col = n0 + j * 16 + r16;
        #pragma unroll
        for (int i = 0; i < 4; ++i) {
            const int row = m0 + i * 16 + quad * 4;
            #pragma unroll
            for (int r = 0; r < 4; ++r)
                po[(size_t)(row + r) * E + col] = acc[i][j][r];
        }
    }
}

// ---------------------------------------------------------------------------
// Kernel 2: emb[b][e] = sum_ks part[ks][b][e] + bias[e]
// ---------------------------------------------------------------------------
__global__ __launch_bounds__(256) void reduce_emb(
    const float* __restrict__ part, const float* __restrict__ bias,
    float* __restrict__ emb)
{
    const int idx = (blockIdx.x * 256 + threadIdx.x) * 4;
    const int col = idx & (E - 1);
    float4 s = *(const float4*)(bias + col);
    #pragma unroll
    for (int ks = 0; ks < KS; ++ks) {
        float4 p = *(const float4*)(part + (size_t)ks * B * E + idx);
        s.x += p.x; s.y += p.y; s.z += p.z; s.w += p.w;
    }
    *(float4*)(emb + idx) = s;
}

// ---------------------------------------------------------------------------
// Kernel 3: neg-score partials.
// grid (8,8,8) = 512 blocks = 2 blocks/CU = 8 waves/CU.
// Tile 64(b) x 64(n), 4x4 v2f accs/thread, one EC=128 chunk per block.
// ---------------------------------------------------------------------------
__global__ __launch_bounds__(256, 2) void scores_part(
    const float* __restrict__ emb,    // [B, E] f32
    const float* __restrict__ n_lfs,  // [N, E] f32
    float* __restrict__ pn)           // [ES, B, N] f32
{
    constexpr int LDW = EC + 2;  // 130
    __shared__ float eS[64 * LDW];
    __shared__ float nS[64 * LDW];

    const int t  = threadIdx.x;
    const int n0 = blockIdx.x * 64;
    const int b0 = blockIdx.y * 64;
    const int e0 = blockIdx.z * EC;

    {
        const int row = t >> 2;            // 0..63
        const int cb  = (t & 3) * 32;      // 0,32,64,96
        const float* ep = emb   + (size_t)(b0 + row) * E + e0 + cb;
        const float* np = n_lfs + (size_t)(n0 + row) * E + e0 + cb;
        float* ed = &eS[row * LDW + cb];
        float* nd = &nS[row * LDW + cb];
        #pragma unroll
        for (int q = 0; q < 8; ++q) {
            float4 v = *(const float4*)(ep + q * 4);
            float4 w = *(const float4*)(np + q * 4);
            *(v2f*)(ed + q * 4)     = (v2f){v.x, v.y};
            *(v2f*)(ed + q * 4 + 2) = (v2f){v.z, v.w};
            *(v2f*)(nd + q * 4)     = (v2f){w.x, w.y};
            *(v2f*)(nd + q * 4 + 2) = (v2f){w.z, w.w};
        }
    }
    __syncthreads();

    const int ty = t >> 4;   // 0..15 -> b rows ty+16r
    const int tx = t & 15;   // 0..15 -> n rows tx+16c

    const v2f z = {0.f, 0.f};
    v2f acc[4][4] = {{z,z,z,z},{z,z,z,z},{z,z,z,z},{z,z,z,z}};

    #pragma unroll 4
    for (int e = 0; e < EC; e += 2) {
        v2f a[4], c[4];
        #pragma unroll
        for (int r = 0; r < 4; ++r)
            a[r] = *(const v2f*)&eS[(ty + 16 * r) * LDW + e];
        #pragma unroll
        for (int q = 0; q < 4; ++q)
            c[q] = *(const v2f*)&nS[(tx + 16 * q) * LDW + e];
        #pragma unroll
        for (int r = 0; r < 4; ++r)
            #pragma unroll
            for (int q = 0; q < 4; ++q) {
                v2f d = c[q] - a[r];
                d = __builtin_elementwise_max(d, z);
                acc[r][q] = __builtin_elementwise_fma(d, d, acc[r][q]);
            }
    }

    float* po = pn + (size_t)blockIdx.z * B * N;
    #pragma unroll
    for (int r = 0; r < 4; ++r) {
        const size_t ob = (size_t)(b0 + ty + 16 * r) * N;
        #pragma unroll
        for (int q = 0; q < 4; ++q)
            po[ob + n0 + tx + 16 * q] = acc[r][q].x + acc[r][q].y;
    }
}

// ---------------------------------------------------------------------------
// Kernel 4: final scores (negatives reduce + positive scores).
// ---------------------------------------------------------------------------
__global__ __launch_bounds__(256) void scores_final(
    const float* __restrict__ pn,     // [ES, B, N]
    const float* __restrict__ emb,    // [B, E]
    const float* __restrict__ p_lfs,  // [B, E]
    float* __restrict__ out)          // [B, 1+N]
{
    const int t = threadIdx.x;
    if (blockIdx.x < 1024) {
        const int i = blockIdx.x * 256 + t;       // 0..B*N-1
        const int b = i >> 9;                     // /N
        const int n = i & (N - 1);
        float s = 0.f;
        #pragma unroll
        for (int z = 0; z < ES; ++z)
            s += pn[(size_t)z * B * N + i];
        out[(size_t)b * 513 + 1 + n] = -sqrtf(s);
        return;
    }
    const int b0 = (blockIdx.x - 1024) * 32;
    const int r = t >> 3;        // 0..31
    const int g = t & 7;         // 8 threads per row
    const float* pr = p_lfs + (size_t)(b0 + r) * E;
    const float* er = emb   + (size_t)(b0 + r) * E;
    float acc = 0.f;
    for (int e = g * 4; e < E; e += 32) {
        float4 p = *(const float4*)(pr + e);
        float4 v = *(const float4*)(er + e);
        float d;
        d = p.x - v.x; d = fmaxf(d, 0.f); acc = fmaf(d, d, acc);
        d = p.y - v.y; d = fmaxf(d, 0.f); acc = fmaf(d, d, acc);
        d = p.z - v.z; d = fmaxf(d, 0.f); acc = fmaf(d, d, acc);
        d = p.w - v.w; d = fmaxf(d, 0.f); acc = fmaf(d, d, acc);
    }
    #pragma unroll
    for (int off = 4; off; off >>= 1) acc += __shfl_down(acc, off, 8);
    if (g == 0) out[(size_t)(b0 + r) * 513] = -sqrtf(acc);
}

extern "C" void kernel_launch(void* const* d_in, const int* in_sizes, int n_in,
                              void* d_out, int out_size, void* d_ws, size_t ws_size,
                              hipStream_t stream) {
    const float* vf    = (const float*)d_in[0];  // [512,4096] f32
    const float* p_lfs = (const float*)d_in[1];  // [512,1024] f32
    const float* n_lfs = (const float*)d_in[2];  // [512,1024] f32
    const float* W     = (const float*)d_in[3];  // [1024,4096] f32
    const float* bias  = (const float*)d_in[4];  // [1024] f32
    float* out = (float*)d_out;                  // [512,513] f32

    // ws layout (30 MB peak):
    //   [0, 16MB): pg   f32 [KS=8,512,1024]  (dead after reduce_emb)
    //   [0,  8MB): pn   f32 [ES=8,512,512]   (overlays dead pg)
    //   [16,20MB): vfB  bf16 [512,4096]
    //   [20,28MB): WB   bf16 [1024,4096]
    //   [28,30MB): emb  f32 [512,1024]
    char* ws = (char*)d_ws;
    float*          pg  = (float*)ws;
    float*          pn  = (float*)ws;
    unsigned short* vfB = (unsigned short*)(ws + ((size_t)16 << 20));
    unsigned short* WB  = (unsigned short*)(ws + ((size_t)20 << 20));
    float*          emb = (float*)(ws + ((size_t)28 << 20));

    cvt_all<<<3072, 256, 0, stream>>>(vf, W, vfB, WB);

    dim3 g1(E / 64, B / 64, KS);   // (16, 8, 8) = 1024 one-wave blocks
    gemm_lds<<<g1, 64, 0, stream>>>(vfB, WB, pg);

    reduce_emb<<<(B * E) / 1024, 256, 0, stream>>>(pg, bias, emb);

    dim3 g3(N / 64, B / 64, ES);   // (8, 8, 8) = 512 blocks
    scores_part<<<g3, 256, 0, stream>>>(emb, n_lfs, pn);

    scores_final<<<1024 + B / 32, 256, 0, stream>>>(pn, emb, p_lfs, out);
}

// Round 4
// 120.738 us; speedup vs baseline: 1.1533x; 1.0996x over previous
//
#include <hip/hip_runtime.h>
#include <hip/hip_bf16.h>

// Problem constants (fixed by setup_inputs)
constexpr int B = 512;   // batch
constexpr int D = 4096;  // D_vis
constexpr int E = 1024;  // embed dim
constexpr int N = 512;   // negatives
constexpr int KS = 8;    // GEMM K-split factor
constexpr int KC = D / KS;      // 512 K per split
constexpr int NSTEP = KC / 32;  // 16 k-steps per wave
constexpr int ES = 8;    // scores E-split factor
constexpr int EC = E / ES;      // 128 e per scores block
constexpr int DEPTH = 4;        // GEMM pipeline depth (LDS buffers)

typedef __attribute__((ext_vector_type(8))) short bf16x8;   // 8 bf16 = 4 VGPRs
typedef __attribute__((ext_vector_type(4))) float f32x4;
typedef _Float16 h2 __attribute__((ext_vector_type(2)));
typedef _Float16 h4 __attribute__((ext_vector_type(4)));
typedef _Float16 h8 __attribute__((ext_vector_type(8)));

typedef __attribute__((address_space(3))) void lds_void;
typedef const __attribute__((address_space(1))) void gbl_void;

__device__ __forceinline__ unsigned short f2bf(float f) {
    __hip_bfloat16 h = __float2bfloat16(f);   // RTNE
    return *reinterpret_cast<unsigned short*>(&h);
}

#if __has_builtin(__builtin_amdgcn_fdot2)
__device__ __forceinline__ float fdot2(h2 a, h2 b, float c) {
    return __builtin_amdgcn_fdot2(a, b, c, false);
}
#else
__device__ __forceinline__ float fdot2(h2 a, h2 b, float c) {
    return c + (float)a[0] * (float)b[0] + (float)a[1] * (float)b[1];
}
#endif

// ---------------------------------------------------------------------------
// Kernel 0: f32 -> bf16 convert for vf and W, f32 -> f16 for n_lfs.
// grid 3328: [0,1024) vf, [1024,3072) W, [3072,3328) n_lfs.
// ---------------------------------------------------------------------------
__global__ __launch_bounds__(256) void cvt_all(
    const float* __restrict__ vf, const float* __restrict__ W,
    const float* __restrict__ n_lfs,
    unsigned short* __restrict__ vfB, unsigned short* __restrict__ WB,
    _Float16* __restrict__ n16)
{
    const int bid = blockIdx.x;
    if (bid < 3072) {
        const float* src;
        unsigned short* dst;
        int i;
        if (bid < 1024) { src = vf; dst = vfB; i = (bid * 256 + threadIdx.x) * 8; }
        else           { src = W;  dst = WB;  i = ((bid - 1024) * 256 + threadIdx.x) * 8; }
        float4 v0 = *(const float4*)(src + i);
        float4 v1 = *(const float4*)(src + i + 4);
        bf16x8 o;
        o[0] = (short)f2bf(v0.x); o[1] = (short)f2bf(v0.y);
        o[2] = (short)f2bf(v0.z); o[3] = (short)f2bf(v0.w);
        o[4] = (short)f2bf(v1.x); o[5] = (short)f2bf(v1.y);
        o[6] = (short)f2bf(v1.z); o[7] = (short)f2bf(v1.w);
        *(bf16x8*)(dst + i) = o;
    } else {
        const int i = ((bid - 3072) * 256 + threadIdx.x) * 8;
        float4 v0 = *(const float4*)(n_lfs + i);
        float4 v1 = *(const float4*)(n_lfs + i + 4);
        h8 o;
        o[0] = (_Float16)v0.x; o[1] = (_Float16)v0.y;
        o[2] = (_Float16)v0.z; o[3] = (_Float16)v0.w;
        o[4] = (_Float16)v1.x; o[5] = (_Float16)v1.y;
        o[6] = (_Float16)v1.z; o[7] = (_Float16)v1.w;
        *(h8*)(n16 + i) = o;
    }
}

// ---------------------------------------------------------------------------
// Kernel 1: K-split GEMM, one wave per block, 64(m) x 64(n) tile, KS=8.
// grid (16,8,8) = 1024 blocks = 4 blocks/CU (1 wave/SIMD).
// r4 change: epilogue transposed through LDS (stride-69 f32 rows; 69 = 5 mod
// 32, gcd(5,32)=1 -> conflict-free) so each lane stores one full 256B row
// with 16x global_store_dwordx4. Kills the RMW fetch of pg lines that r1
// counters showed (FETCH 28MB vs 12MB unique) and the slow 4B-scatter drain.
// K-pipeline unchanged from r3 (depth 4, vmcnt(24) steady, peeled tail).
// LDS layout (staging): tile as 16B chunks, chunk(row, qs) at (row*4+qs)*16,
// holding global (row, q) where q = qs ^ (row&3) ^ ((row>>2)&3).
// A-frag: A[m=lane&15][k=quad*8+j]; B-frag: B[k=quad*8+j][n=lane&15].
// C/D: col=lane&15, row=quad*4+reg  [verified prior session]
// ---------------------------------------------------------------------------
__global__ __launch_bounds__(64) void gemm_lds(
    const unsigned short* __restrict__ vf,    // [B, D] bf16 bits
    const unsigned short* __restrict__ W,     // [E, D] bf16 bits
    float* __restrict__ part)                 // [KS, B, E] f32
{
    // 32 KB: [0,16K) = sA (DEPTH x 4KB), [16K,32K) = sB. Epilogue reuses
    // [0, 17664) as 64x69 f32 transpose buffer.
    __shared__ __align__(16) char smem[32768];

    const int L  = threadIdx.x;

    // ---- XCD-chunked swizzle: linear id -> logical tile ----
    // id in [0,1024); HW XCD ~ id%8. logical l = (id%8)*128 + id/8;
    // ks = l>>7 (fixed per XCD), n-block = l&15, m-block = (l>>4)&7.
    const int id = blockIdx.x + 16 * blockIdx.y + 128 * blockIdx.z;
    const int l  = (id & 7) * 128 + (id >> 3);
    const int ks = l >> 7;
    const int n0 = (l & 15) * 64;
    const int m0 = ((l >> 4) & 7) * 64;

    // ---- staging addresses ----
    const int subrow = L >> 2;                                  // 0..15
    const int qstg = (L & 3) ^ ((L >> 2) & 3) ^ ((L >> 4) & 3); // swizzled k-group
    const int kbeg = ks * KC;
    const unsigned short* aSrc[4];
    const unsigned short* bSrc[4];
    #pragma unroll
    for (int c = 0; c < 4; ++c) {
        aSrc[c] = vf + (size_t)(m0 + c * 16 + subrow) * D + kbeg + qstg * 8;
        bSrc[c] = W  + (size_t)(n0 + c * 16 + subrow) * D + kbeg + qstg * 8;
    }

    // ---- fragment read offsets ----
    const int r16 = L & 15;
    const int quad = L >> 4;
    const int swz = quad ^ (r16 & 3) ^ ((r16 >> 2) & 3);
    const int aoff = r16 * 64 + swz * 16;   // byte offset within a buffer

    f32x4 acc[4][4] = {};

    auto issue = [&](int step, int buf) {
        const size_t koff = (size_t)step * 32;   // elements
        #pragma unroll
        for (int c = 0; c < 4; ++c) {
            __builtin_amdgcn_global_load_lds(
                (gbl_void*)(aSrc[c] + koff),
                (lds_void*)(smem + buf * 4096 + c * 1024), 16, 0, 0);
            __builtin_amdgcn_global_load_lds(
                (gbl_void*)(bSrc[c] + koff),
                (lds_void*)(smem + 16384 + buf * 4096 + c * 1024), 16, 0, 0);
        }
    };

    issue(0, 0);
    issue(1, 1);
    issue(2, 2);
    issue(3, 3);

    // waitcnt imm (gfx9): vmcnt split [3:0]+[15:14], exp [6:4], lgkm [11:8].
    //   vmcnt(24)=0x4F78, vmcnt(16)=0x4F70, vmcnt(8)=0x0F78, vmcnt(0)=0x0F70
    #define GSTEP(S, WC, ISS)                                                  \
    {                                                                          \
        const int buf_ = (S) & 3;                                              \
        __builtin_amdgcn_s_waitcnt(WC);                                        \
        bf16x8 af[4], bg[4];                                                   \
        _Pragma("unroll")                                                      \
        for (int i = 0; i < 4; ++i)                                            \
            af[i] = *(const bf16x8*)(smem + buf_ * 4096 + i * 1024 + aoff);    \
        _Pragma("unroll")                                                      \
        for (int j = 0; j < 4; ++j)                                            \
            bg[j] = *(const bf16x8*)(smem + 16384 + buf_ * 4096 + j * 1024 + aoff); \
        _Pragma("unroll")                                                      \
        for (int i = 0; i < 4; ++i)                                            \
            _Pragma("unroll")                                                  \
            for (int j = 0; j < 4; ++j)                                        \
                acc[i][j] = __builtin_amdgcn_mfma_f32_16x16x32_bf16(           \
                    af[i], bg[j], acc[i][j], 0, 0, 0);                         \
        if (ISS) issue((S) + DEPTH, buf_);                                     \
    }

    #pragma unroll 1
    for (int s = 0; s < NSTEP - DEPTH; ++s)
        GSTEP(s, 0x4F78, true);              // steady state: vmcnt(24)
    GSTEP(NSTEP - 4, 0x4F78, false);         // vmcnt(24)
    GSTEP(NSTEP - 3, 0x4F70, false);         // vmcnt(16)
    GSTEP(NSTEP - 2, 0x0F78, false);         // vmcnt(8)
    GSTEP(NSTEP - 1, 0x0F70, false);         // vmcnt(0): all staging drained
    #undef GSTEP

    // ---- coalesced epilogue: acc -> LDS (stride 69) -> row-major stores ----
    float* ct = (float*)smem;   // 64 x 69 f32 = 17664 B (staging is dead)
    #pragma unroll
    for (int i = 0; i < 4; ++i)
        #pragma unroll
        for (int j = 0; j < 4; ++j)
            #pragma unroll
            for (int r = 0; r < 4; ++r)
                ct[(i * 16 + quad * 4 + r) * 69 + (j * 16 + r16)] = acc[i][j][r];
    __builtin_amdgcn_s_waitcnt(0xC07F);      // lgkmcnt(0): ds_writes visible
    __builtin_amdgcn_sched_barrier(0);
    float* po = part + (size_t)ks * B * E + (size_t)(m0 + L) * E + n0;
    const float* crow = ct + L * 69;
    #pragma unroll
    for (int c4 = 0; c4 < 16; ++c4) {
        f32x4 v;
        v[0] = crow[c4 * 4];     v[1] = crow[c4 * 4 + 1];
        v[2] = crow[c4 * 4 + 2]; v[3] = crow[c4 * 4 + 3];
        *(f32x4*)(po + c4 * 4) = v;          // full-line dwordx4, no RMW
    }
}

// ---------------------------------------------------------------------------
// Kernel 2: one block per batch row b (grid = 512):
//   s = sum_ks part[ks][b][:] + bias  -> emb16[b][:] (f16)
//   p_score[b] = -||relu(p_lfs[b] - s)|| -> out[b*513]  (s in full f32)
// ---------------------------------------------------------------------------
__global__ __launch_bounds__(256) void reduce_emb(
    const float* __restrict__ part, const float* __restrict__ bias,
    const float* __restrict__ p_lfs,
    _Float16* __restrict__ emb16, float* __restrict__ out)
{
    const int b = blockIdx.x;
    const int e = threadIdx.x * 4;
    const size_t base = (size_t)b * E + e;
    float4 s = *(const float4*)(bias + e);
    #pragma unroll
    for (int ks = 0; ks < KS; ++ks) {
        float4 p = *(const float4*)(part + (size_t)ks * B * E + base);
        s.x += p.x; s.y += p.y; s.z += p.z; s.w += p.w;
    }
    h4 o;
    o[0] = (_Float16)s.x; o[1] = (_Float16)s.y;
    o[2] = (_Float16)s.z; o[3] = (_Float16)s.w;
    *(h4*)(emb16 + base) = o;

    // positive score for row b
    const float4 pl = *(const float4*)(p_lfs + base);
    float d, a = 0.f;
    d = pl.x - s.x; d = fmaxf(d, 0.f); a = fmaf(d, d, a);
    d = pl.y - s.y; d = fmaxf(d, 0.f); a = fmaf(d, d, a);
    d = pl.z - s.z; d = fmaxf(d, 0.f); a = fmaf(d, d, a);
    d = pl.w - s.w; d = fmaxf(d, 0.f); a = fmaf(d, d, a);
    #pragma unroll
    for (int off = 32; off; off >>= 1) a += __shfl_down(a, off, 64);
    __shared__ float red[4];
    if ((threadIdx.x & 63) == 0) red[threadIdx.x >> 6] = a;
    __syncthreads();
    if (threadIdx.x == 0)
        out[(size_t)b * 513] = -sqrtf(red[0] + red[1] + red[2] + red[3]);
}

// ---------------------------------------------------------------------------
// Kernel 3: neg-score partials, f16 math with v_dot2_f32_f16 (f32 accum).
// grid (8,8,8) = 512 blocks. Tile 64(b) x 64(n), 4x4 f32 accs/thread,
// one EC=128 chunk per block. eS stores NEGATED emb so inner loop is
// d = n + (-e) (v_pk_add_f16), relu (v_pk_max_f16), acc = fdot2(d,d,acc).
// 3 instrs / 2 elems vs ~6 scalar f32 -> ~2x VALU cut; LDS halves.
// ---------------------------------------------------------------------------
__global__ __launch_bounds__(256, 4) void scores_part(
    const _Float16* __restrict__ emb16,  // [B, E] f16
    const _Float16* __restrict__ n16,    // [N, E] f16
    float* __restrict__ pn)              // [ES, B, N] f32
{
    constexpr int LDH = EC + 8;  // 136 halfs; row stride 272B = 68 words
    __shared__ _Float16 eS[64 * LDH];
    __shared__ _Float16 nS[64 * LDH];

    const int t  = threadIdx.x;
    const int n0 = blockIdx.x * 64;
    const int b0 = blockIdx.y * 64;
    const int e0 = blockIdx.z * EC;

    {
        const int row = t >> 2;            // 0..63
        const int cb  = (t & 3) * 32;      // halfs: 0,32,64,96
        const _Float16* ep = emb16 + (size_t)(b0 + row) * E + e0 + cb;
        const _Float16* np = n16   + (size_t)(n0 + row) * E + e0 + cb;
        _Float16* ed = &eS[row * LDH + cb];
        _Float16* nd = &nS[row * LDH + cb];
        #pragma unroll
        for (int q = 0; q < 4; ++q) {
            h8 v = *(const h8*)(ep + q * 8);
            h8 w = *(const h8*)(np + q * 8);
            *(h8*)(ed + q * 8) = -v;       // pre-negated emb
            *(h8*)(nd + q * 8) = w;
        }
    }
    __syncthreads();

    const int ty = t >> 4;   // 0..15 -> b rows ty+16r
    const int tx = t & 15;   // 0..15 -> n rows tx+16q

    float acc[4][4] = {};
    const h4 z4 = {};

    #pragma unroll 2
    for (int e = 0; e < EC; e += 4) {
        h4 a[4], c[4];
        #pragma unroll
        for (int r = 0; r < 4; ++r)
            a[r] = *(const h4*)&eS[(ty + 16 * r) * LDH + e];
        #pragma unroll
        for (int q = 0; q < 4; ++q)
            c[q] = *(const h4*)&nS[(tx + 16 * q) * LDH + e];
        #pragma unroll
        for (int r = 0; r < 4; ++r)
            #pragma unroll
            for (int q = 0; q < 4; ++q) {
                h4 d = c[q] + a[r];                       // n - e
                d = __builtin_elementwise_max(d, z4);     // relu
                h2 dl = __builtin_shufflevector(d, d, 0, 1);
                h2 dh = __builtin_shufflevector(d, d, 2, 3);
                acc[r][q] = fdot2(dl, dl, acc[r][q]);
                acc[r][q] = fdot2(dh, dh, acc[r][q]);
            }
    }

    float* po = pn + (size_t)blockIdx.z * B * N;
    #pragma unroll
    for (int r = 0; r < 4; ++r) {
        const size_t ob = (size_t)(b0 + ty + 16 * r) * N;
        #pragma unroll
        for (int q = 0; q < 4; ++q)
            po[ob + n0 + tx + 16 * q] = acc[r][q];
    }
}

// ---------------------------------------------------------------------------
// Kernel 4: negative-score reduce over ES parts (positives done in K2).
// ---------------------------------------------------------------------------
__global__ __launch_bounds__(256) void scores_final(
    const float* __restrict__ pn,     // [ES, B, N]
    float* __restrict__ out)          // [B, 1+N]
{
    const int i = blockIdx.x * 256 + threadIdx.x;   // 0..B*N-1
    const int b = i >> 9;                           // /N
    const int n = i & (N - 1);
    float s = 0.f;
    #pragma unroll
    for (int z = 0; z < ES; ++z)
        s += pn[(size_t)z * B * N + i];
    out[(size_t)b * 513 + 1 + n] = -sqrtf(s);
}

extern "C" void kernel_launch(void* const* d_in, const int* in_sizes, int n_in,
                              void* d_out, int out_size, void* d_ws, size_t ws_size,
                              hipStream_t stream) {
    const float* vf    = (const float*)d_in[0];  // [512,4096] f32
    const float* p_lfs = (const float*)d_in[1];  // [512,1024] f32
    const float* n_lfs = (const float*)d_in[2];  // [512,1024] f32
    const float* W     = (const float*)d_in[3];  // [1024,4096] f32
    const float* bias  = (const float*)d_in[4];  // [1024] f32
    float* out = (float*)d_out;                  // [512,513] f32

    // ws layout (30 MB peak):
    //   [0, 16MB): pg    f32 [KS=8,512,1024]  (dead after reduce_emb)
    //   [0,  8MB): pn    f32 [ES=8,512,512]   (overlays dead pg)
    //   [16,20MB): vfB   bf16 [512,4096]
    //   [20,28MB): WB    bf16 [1024,4096]
    //   [28,29MB): emb16 f16 [512,1024]
    //   [29,30MB): n16   f16 [512,1024]
    char* ws = (char*)d_ws;
    float*          pg    = (float*)ws;
    float*          pn    = (float*)ws;
    unsigned short* vfB   = (unsigned short*)(ws + ((size_t)16 << 20));
    unsigned short* WB    = (unsigned short*)(ws + ((size_t)20 << 20));
    _Float16*       emb16 = (_Float16*)(ws + ((size_t)28 << 20));
    _Float16*       n16   = (_Float16*)(ws + ((size_t)29 << 20));

    cvt_all<<<3328, 256, 0, stream>>>(vf, W, n_lfs, vfB, WB, n16);

    dim3 g1(E / 64, B / 64, KS);   // (16, 8, 8) = 1024 one-wave blocks
    gemm_lds<<<g1, 64, 0, stream>>>(vfB, WB, pg);

    reduce_emb<<<B, 256, 0, stream>>>(pg, bias, p_lfs, emb16, out);

    dim3 g3(N / 64, B / 64, ES);   // (8, 8, 8) = 512 blocks
    scores_part<<<g3, 256, 0, stream>>>(emb16, n16, pn);

    scores_final<<<(B * N) / 256, 256, 0, stream>>>(pn, out);
}

// Round 5
// 118.219 us; speedup vs baseline: 1.1779x; 1.0213x over previous
//
#include <hip/hip_runtime.h>
#include <hip/hip_bf16.h>

// Problem constants (fixed by setup_inputs)
constexpr int B = 512;   // batch
constexpr int D = 4096;  // D_vis
constexpr int E = 1024;  // embed dim
constexpr int N = 512;   // negatives
constexpr int KS = 16;   // GEMM K-split (r5: 8 -> 16 => 2048 blocks = 2 waves/SIMD)
constexpr int KC = D / KS;      // 256 K per split
constexpr int NSTEP = KC / 32;  // 8 k-steps per wave
constexpr int ES = 8;    // scores E-split factor
constexpr int EC = E / ES;      // 128 e per scores block
constexpr int DEPTH = 2;        // GEMM pipeline depth (LDS halved to fit 8 blocks/CU)

typedef __attribute__((ext_vector_type(8))) short bf16x8;   // 8 bf16 = 4 VGPRs
typedef __attribute__((ext_vector_type(4))) float f32x4;
typedef _Float16 h2 __attribute__((ext_vector_type(2)));
typedef _Float16 h4 __attribute__((ext_vector_type(4)));
typedef _Float16 h8 __attribute__((ext_vector_type(8)));

typedef __attribute__((address_space(3))) void lds_void;
typedef const __attribute__((address_space(1))) void gbl_void;

__device__ __forceinline__ unsigned short f2bf(float f) {
    __hip_bfloat16 h = __float2bfloat16(f);   // RTNE
    return *reinterpret_cast<unsigned short*>(&h);
}

#if __has_builtin(__builtin_amdgcn_fdot2)
__device__ __forceinline__ float fdot2(h2 a, h2 b, float c) {
    return __builtin_amdgcn_fdot2(a, b, c, false);
}
#else
__device__ __forceinline__ float fdot2(h2 a, h2 b, float c) {
    return c + (float)a[0] * (float)b[0] + (float)a[1] * (float)b[1];
}
#endif

// ---------------------------------------------------------------------------
// Kernel 0: f32 -> bf16 convert for vf and W, f32 -> f16 for n_lfs.
// grid 3328: [0,1024) vf, [1024,3072) W, [3072,3328) n_lfs.
// ---------------------------------------------------------------------------
__global__ __launch_bounds__(256) void cvt_all(
    const float* __restrict__ vf, const float* __restrict__ W,
    const float* __restrict__ n_lfs,
    unsigned short* __restrict__ vfB, unsigned short* __restrict__ WB,
    _Float16* __restrict__ n16)
{
    const int bid = blockIdx.x;
    if (bid < 3072) {
        const float* src;
        unsigned short* dst;
        int i;
        if (bid < 1024) { src = vf; dst = vfB; i = (bid * 256 + threadIdx.x) * 8; }
        else           { src = W;  dst = WB;  i = ((bid - 1024) * 256 + threadIdx.x) * 8; }
        float4 v0 = *(const float4*)(src + i);
        float4 v1 = *(const float4*)(src + i + 4);
        bf16x8 o;
        o[0] = (short)f2bf(v0.x); o[1] = (short)f2bf(v0.y);
        o[2] = (short)f2bf(v0.z); o[3] = (short)f2bf(v0.w);
        o[4] = (short)f2bf(v1.x); o[5] = (short)f2bf(v1.y);
        o[6] = (short)f2bf(v1.z); o[7] = (short)f2bf(v1.w);
        *(bf16x8*)(dst + i) = o;
    } else {
        const int i = ((bid - 3072) * 256 + threadIdx.x) * 8;
        float4 v0 = *(const float4*)(n_lfs + i);
        float4 v1 = *(const float4*)(n_lfs + i + 4);
        h8 o;
        o[0] = (_Float16)v0.x; o[1] = (_Float16)v0.y;
        o[2] = (_Float16)v0.z; o[3] = (_Float16)v0.w;
        o[4] = (_Float16)v1.x; o[5] = (_Float16)v1.y;
        o[6] = (_Float16)v1.z; o[7] = (_Float16)v1.w;
        *(h8*)(n16 + i) = o;
    }
}

// ---------------------------------------------------------------------------
// Kernel 1: K-split GEMM, one wave per block, 64(m) x 64(n) tile, KS=16.
// grid (16,8,16) = 2048 blocks = 8 blocks/CU = 2 waves/SIMD.
// r5 theory: 1 wave/SIMD (r3/r4) gave zero same-SIMD TLP -- a vmcnt-stalled
// wave idles its SIMD. 2048 blocks puts 2 waves on each SIMD so stalls
// overlap with the co-resident wave's MFMA. DEPTH=2 (16KB staging + 1.6KB
// epilogue slack = 17.6KB LDS/block; 8x17.6 = 141KB <= 160KB/CU).
// pg is f16 now (partials ~N(0,0.5), f16 rel err 5e-4 -- emb is f16 anyway).
//  (a) XCD-chunked swizzle: l=(id%8)*256+id/8; ks=l>>7 (2 per XCD),
//      n0=(l&15)*64, m0=((l>>4)&7)*64. Per-XCD ws = 0.5MB A + 1MB B < 4MB L2.
//  (b) steady-state vmcnt(8), last step vmcnt(0).
// LDS staging layout + fragment mapping unchanged (verified prior session).
// C/D: col=lane&15, row=quad*4+reg.
// ---------------------------------------------------------------------------
__global__ __launch_bounds__(64) void gemm_lds(
    const unsigned short* __restrict__ vf,    // [B, D] bf16 bits
    const unsigned short* __restrict__ W,     // [E, D] bf16 bits
    _Float16* __restrict__ part)              // [KS, B, E] f16
{
    // [0,8K) = sA (2 x 4KB), [8K,16K) = sB (2 x 4KB).
    // Epilogue reuses [0,17664) as 64x69 f32 transpose buffer.
    __shared__ __align__(16) char smem[17664];

    const int L  = threadIdx.x;

    const int id = blockIdx.x + 16 * blockIdx.y + 128 * blockIdx.z;
    const int l  = (id & 7) * 256 + (id >> 3);
    const int ks = l >> 7;
    const int n0 = (l & 15) * 64;
    const int m0 = ((l >> 4) & 7) * 64;

    // ---- staging addresses ----
    const int subrow = L >> 2;                                  // 0..15
    const int qstg = (L & 3) ^ ((L >> 2) & 3) ^ ((L >> 4) & 3); // swizzled k-group
    const int kbeg = ks * KC;
    const unsigned short* aSrc[4];
    const unsigned short* bSrc[4];
    #pragma unroll
    for (int c = 0; c < 4; ++c) {
        aSrc[c] = vf + (size_t)(m0 + c * 16 + subrow) * D + kbeg + qstg * 8;
        bSrc[c] = W  + (size_t)(n0 + c * 16 + subrow) * D + kbeg + qstg * 8;
    }

    // ---- fragment read offsets ----
    const int r16 = L & 15;
    const int quad = L >> 4;
    const int swz = quad ^ (r16 & 3) ^ ((r16 >> 2) & 3);
    const int aoff = r16 * 64 + swz * 16;   // byte offset within a buffer

    f32x4 acc[4][4] = {};

    auto issue = [&](int step, int buf) {
        const size_t koff = (size_t)step * 32;   // elements
        #pragma unroll
        for (int c = 0; c < 4; ++c) {
            __builtin_amdgcn_global_load_lds(
                (gbl_void*)(aSrc[c] + koff),
                (lds_void*)(smem + buf * 4096 + c * 1024), 16, 0, 0);
            __builtin_amdgcn_global_load_lds(
                (gbl_void*)(bSrc[c] + koff),
                (lds_void*)(smem + 8192 + buf * 4096 + c * 1024), 16, 0, 0);
        }
    };

    issue(0, 0);
    issue(1, 1);

    // waitcnt imm (gfx9): vmcnt split [3:0]+[15:14], exp [6:4], lgkm [11:8].
    //   vmcnt(8)=0x0F78, vmcnt(0)=0x0F70
    #define GSTEP(S, WC, ISS)                                                  \
    {                                                                          \
        const int buf_ = (S) & 1;                                              \
        __builtin_amdgcn_s_waitcnt(WC);                                        \
        bf16x8 af[4], bg[4];                                                   \
        _Pragma("unroll")                                                      \
        for (int i = 0; i < 4; ++i)                                            \
            af[i] = *(const bf16x8*)(smem + buf_ * 4096 + i * 1024 + aoff);    \
        _Pragma("unroll")                                                      \
        for (int j = 0; j < 4; ++j)                                            \
            bg[j] = *(const bf16x8*)(smem + 8192 + buf_ * 4096 + j * 1024 + aoff); \
        _Pragma("unroll")                                                      \
        for (int i = 0; i < 4; ++i)                                            \
            _Pragma("unroll")                                                  \
            for (int j = 0; j < 4; ++j)                                        \
                acc[i][j] = __builtin_amdgcn_mfma_f32_16x16x32_bf16(           \
                    af[i], bg[j], acc[i][j], 0, 0, 0);                         \
        if (ISS) issue((S) + DEPTH, buf_);                                     \
    }

    #pragma unroll 1
    for (int s = 0; s < NSTEP - 1; ++s)
        GSTEP(s, 0x0F78, s + DEPTH < NSTEP);   // steady: vmcnt(8)
    GSTEP(NSTEP - 1, 0x0F70, false);           // vmcnt(0): staging drained
    #undef GSTEP

    // ---- coalesced epilogue: acc -> LDS f32 (stride 69, 69%32=5 coprime ->
    // conflict-free) -> per-lane row, pack f16, 8x dwordx4 stores ----
    float* ct = (float*)smem;   // 64 x 69 f32 = 17664 B (staging dead)
    #pragma unroll
    for (int i = 0; i < 4; ++i)
        #pragma unroll
        for (int j = 0; j < 4; ++j)
            #pragma unroll
            for (int r = 0; r < 4; ++r)
                ct[(i * 16 + quad * 4 + r) * 69 + (j * 16 + r16)] = acc[i][j][r];
    __builtin_amdgcn_s_waitcnt(0xC07F);      // lgkmcnt(0): ds_writes visible
    __builtin_amdgcn_sched_barrier(0);
    _Float16* po = part + (size_t)ks * B * E + (size_t)(m0 + L) * E + n0;
    const float* crow = ct + L * 69;
    #pragma unroll
    for (int c8 = 0; c8 < 8; ++c8) {
        h8 v;
        #pragma unroll
        for (int u = 0; u < 8; ++u) v[u] = (_Float16)crow[c8 * 8 + u];
        *(h8*)(po + c8 * 8) = v;             // 16B stores, full lines
    }
}

// ---------------------------------------------------------------------------
// Kernel 2: one block per batch row b (grid = 512):
//   s = sum_ks part[ks][b][:] + bias  -> emb16[b][:] (f16)
//   p_score[b] = -||relu(p_lfs[b] - s)|| -> out[b*513]  (s in full f32)
// ---------------------------------------------------------------------------
__global__ __launch_bounds__(256) void reduce_emb(
    const _Float16* __restrict__ part, const float* __restrict__ bias,
    const float* __restrict__ p_lfs,
    _Float16* __restrict__ emb16, float* __restrict__ out)
{
    const int b = blockIdx.x;
    const int e = threadIdx.x * 4;
    const size_t base = (size_t)b * E + e;
    float4 s = *(const float4*)(bias + e);
    #pragma unroll
    for (int ks = 0; ks < KS; ++ks) {
        h4 p = *(const h4*)(part + (size_t)ks * B * E + base);
        s.x += (float)p[0]; s.y += (float)p[1];
        s.z += (float)p[2]; s.w += (float)p[3];
    }
    h4 o;
    o[0] = (_Float16)s.x; o[1] = (_Float16)s.y;
    o[2] = (_Float16)s.z; o[3] = (_Float16)s.w;
    *(h4*)(emb16 + base) = o;

    // positive score for row b
    const float4 pl = *(const float4*)(p_lfs + base);
    float d, a = 0.f;
    d = pl.x - s.x; d = fmaxf(d, 0.f); a = fmaf(d, d, a);
    d = pl.y - s.y; d = fmaxf(d, 0.f); a = fmaf(d, d, a);
    d = pl.z - s.z; d = fmaxf(d, 0.f); a = fmaf(d, d, a);
    d = pl.w - s.w; d = fmaxf(d, 0.f); a = fmaf(d, d, a);
    #pragma unroll
    for (int off = 32; off; off >>= 1) a += __shfl_down(a, off, 64);
    __shared__ float red[4];
    if ((threadIdx.x & 63) == 0) red[threadIdx.x >> 6] = a;
    __syncthreads();
    if (threadIdx.x == 0)
        out[(size_t)b * 513] = -sqrtf(red[0] + red[1] + red[2] + red[3]);
}

// ---------------------------------------------------------------------------
// Kernel 3: neg-score partials, f16 math with v_dot2_f32_f16 (f32 accum).
// grid (8,8,8) = 512 blocks. Tile 64(b) x 64(n), 4x4 f32 accs/thread,
// one EC=128 chunk per block. eS stores NEGATED emb so inner loop is
// d = n + (-e) (v_pk_add_f16), relu (v_pk_max_f16), acc = fdot2(d,d,acc).
// pn stored f16 (chunk sums ~128, ulp 0.0625 -> final err ~4e-3 << thr).
// ---------------------------------------------------------------------------
__global__ __launch_bounds__(256, 4) void scores_part(
    const _Float16* __restrict__ emb16,  // [B, E] f16
    const _Float16* __restrict__ n16,    // [N, E] f16
    _Float16* __restrict__ pn)           // [ES, B, N] f16
{
    constexpr int LDH = EC + 8;  // 136 halfs
    __shared__ _Float16 eS[64 * LDH];
    __shared__ _Float16 nS[64 * LDH];

    const int t  = threadIdx.x;
    const int n0 = blockIdx.x * 64;
    const int b0 = blockIdx.y * 64;
    const int e0 = blockIdx.z * EC;

    {
        const int row = t >> 2;            // 0..63
        const int cb  = (t & 3) * 32;      // halfs: 0,32,64,96
        const _Float16* ep = emb16 + (size_t)(b0 + row) * E + e0 + cb;
        const _Float16* np = n16   + (size_t)(n0 + row) * E + e0 + cb;
        _Float16* ed = &eS[row * LDH + cb];
        _Float16* nd = &nS[row * LDH + cb];
        #pragma unroll
        for (int q = 0; q < 4; ++q) {
            h8 v = *(const h8*)(ep + q * 8);
            h8 w = *(const h8*)(np + q * 8);
            *(h8*)(ed + q * 8) = -v;       // pre-negated emb
            *(h8*)(nd + q * 8) = w;
        }
    }
    __syncthreads();

    const int ty = t >> 4;   // 0..15 -> b rows ty+16r
    const int tx = t & 15;   // 0..15 -> n rows tx+16q

    float acc[4][4] = {};
    const h4 z4 = {};

    #pragma unroll 2
    for (int e = 0; e < EC; e += 4) {
        h4 a[4], c[4];
        #pragma unroll
        for (int r = 0; r < 4; ++r)
            a[r] = *(const h4*)&eS[(ty + 16 * r) * LDH + e];
        #pragma unroll
        for (int q = 0; q < 4; ++q)
            c[q] = *(const h4*)&nS[(tx + 16 * q) * LDH + e];
        #pragma unroll
        for (int r = 0; r < 4; ++r)
            #pragma unroll
            for (int q = 0; q < 4; ++q) {
                h4 d = c[q] + a[r];                       // n - e
                d = __builtin_elementwise_max(d, z4);     // relu
                h2 dl = __builtin_shufflevector(d, d, 0, 1);
                h2 dh = __builtin_shufflevector(d, d, 2, 3);
                acc[r][q] = fdot2(dl, dl, acc[r][q]);
                acc[r][q] = fdot2(dh, dh, acc[r][q]);
            }
    }

    _Float16* po = pn + (size_t)blockIdx.z * B * N;
    #pragma unroll
    for (int r = 0; r < 4; ++r) {
        const size_t ob = (size_t)(b0 + ty + 16 * r) * N;
        #pragma unroll
        for (int q = 0; q < 4; ++q)
            po[ob + n0 + tx + 16 * q] = (_Float16)acc[r][q];
    }
}

// ---------------------------------------------------------------------------
// Kernel 4: negative-score reduce over ES parts (positives done in K2).
// ---------------------------------------------------------------------------
__global__ __launch_bounds__(256) void scores_final(
    const _Float16* __restrict__ pn,  // [ES, B, N] f16
    float* __restrict__ out)          // [B, 1+N]
{
    const int i = blockIdx.x * 256 + threadIdx.x;   // 0..B*N-1
    const int b = i >> 9;                           // /N
    const int n = i & (N - 1);
    float s = 0.f;
    #pragma unroll
    for (int z = 0; z < ES; ++z)
        s += (float)pn[(size_t)z * B * N + i];
    out[(size_t)b * 513 + 1 + n] = -sqrtf(s);
}

extern "C" void kernel_launch(void* const* d_in, const int* in_sizes, int n_in,
                              void* d_out, int out_size, void* d_ws, size_t ws_size,
                              hipStream_t stream) {
    const float* vf    = (const float*)d_in[0];  // [512,4096] f32
    const float* p_lfs = (const float*)d_in[1];  // [512,1024] f32
    const float* n_lfs = (const float*)d_in[2];  // [512,1024] f32
    const float* W     = (const float*)d_in[3];  // [1024,4096] f32
    const float* bias  = (const float*)d_in[4];  // [1024] f32
    float* out = (float*)d_out;                  // [512,513] f32

    // ws layout (30 MB peak):
    //   [0, 16MB): pg    f16 [KS=16,512,1024]  (dead after reduce_emb)
    //   [0,  4MB): pn    f16 [ES=8,512,512]    (overlays dead pg)
    //   [16,20MB): vfB   bf16 [512,4096]
    //   [20,28MB): WB    bf16 [1024,4096]
    //   [28,29MB): emb16 f16 [512,1024]
    //   [29,30MB): n16   f16 [512,1024]
    char* ws = (char*)d_ws;
    _Float16*       pg    = (_Float16*)ws;
    _Float16*       pn    = (_Float16*)ws;
    unsigned short* vfB   = (unsigned short*)(ws + ((size_t)16 << 20));
    unsigned short* WB    = (unsigned short*)(ws + ((size_t)20 << 20));
    _Float16*       emb16 = (_Float16*)(ws + ((size_t)28 << 20));
    _Float16*       n16   = (_Float16*)(ws + ((size_t)29 << 20));

    cvt_all<<<3328, 256, 0, stream>>>(vf, W, n_lfs, vfB, WB, n16);

    dim3 g1(E / 64, B / 64, KS);   // (16, 8, 16) = 2048 one-wave blocks
    gemm_lds<<<g1, 64, 0, stream>>>(vfB, WB, pg);

    reduce_emb<<<B, 256, 0, stream>>>(pg, bias, p_lfs, emb16, out);

    dim3 g3(N / 64, B / 64, ES);   // (8, 8, 8) = 512 blocks
    scores_part<<<g3, 256, 0, stream>>>(emb16, n16, pn);

    scores_final<<<(B * N) / 256, 256, 0, stream>>>(pn, out);
}

// Round 6
// 113.397 us; speedup vs baseline: 1.2280x; 1.0425x over previous
//
#include <hip/hip_runtime.h>
#include <hip/hip_bf16.h>

// Problem constants (fixed by setup_inputs)
constexpr int B = 512;   // batch
constexpr int D = 4096;  // D_vis
constexpr int E = 1024;  // embed dim
constexpr int N = 512;   // negatives
constexpr int KSW = 16;  // total K-chunks (one per wave)
constexpr int KSG = 4;   // global partial slices (after in-block 4-wave reduce)
constexpr int KC = D / KSW;     // 256 K per wave
constexpr int NSTEP = KC / 32;  // 8 k-steps per wave
constexpr int ES = 8;    // scores E-split factor
constexpr int EC = E / ES;      // 128 e per scores block
constexpr int DEPTH = 2;        // GEMM pipeline depth per wave

typedef __attribute__((ext_vector_type(8))) short bf16x8;   // 8 bf16 = 4 VGPRs
typedef __attribute__((ext_vector_type(4))) float f32x4;
typedef _Float16 h2 __attribute__((ext_vector_type(2)));
typedef _Float16 h4 __attribute__((ext_vector_type(4)));
typedef _Float16 h8 __attribute__((ext_vector_type(8)));

typedef __attribute__((address_space(3))) void lds_void;
typedef const __attribute__((address_space(1))) void gbl_void;

__device__ __forceinline__ unsigned short f2bf(float f) {
    __hip_bfloat16 h = __float2bfloat16(f);   // RTNE
    return *reinterpret_cast<unsigned short*>(&h);
}

#if __has_builtin(__builtin_amdgcn_fdot2)
__device__ __forceinline__ float fdot2(h2 a, h2 b, float c) {
    return __builtin_amdgcn_fdot2(a, b, c, false);
}
#else
__device__ __forceinline__ float fdot2(h2 a, h2 b, float c) {
    return c + (float)a[0] * (float)b[0] + (float)a[1] * (float)b[1];
}
#endif

// ---------------------------------------------------------------------------
// Kernel 0: f32 -> bf16 convert for vf and W, f32 -> f16 for n_lfs.
// grid 3328: [0,1024) vf, [1024,3072) W, [3072,3328) n_lfs.
// ---------------------------------------------------------------------------
__global__ __launch_bounds__(256) void cvt_all(
    const float* __restrict__ vf, const float* __restrict__ W,
    const float* __restrict__ n_lfs,
    unsigned short* __restrict__ vfB, unsigned short* __restrict__ WB,
    _Float16* __restrict__ n16)
{
    const int bid = blockIdx.x;
    if (bid < 3072) {
        const float* src;
        unsigned short* dst;
        int i;
        if (bid < 1024) { src = vf; dst = vfB; i = (bid * 256 + threadIdx.x) * 8; }
        else           { src = W;  dst = WB;  i = ((bid - 1024) * 256 + threadIdx.x) * 8; }
        float4 v0 = *(const float4*)(src + i);
        float4 v1 = *(const float4*)(src + i + 4);
        bf16x8 o;
        o[0] = (short)f2bf(v0.x); o[1] = (short)f2bf(v0.y);
        o[2] = (short)f2bf(v0.z); o[3] = (short)f2bf(v0.w);
        o[4] = (short)f2bf(v1.x); o[5] = (short)f2bf(v1.y);
        o[6] = (short)f2bf(v1.z); o[7] = (short)f2bf(v1.w);
        *(bf16x8*)(dst + i) = o;
    } else {
        const int i = ((bid - 3072) * 256 + threadIdx.x) * 8;
        float4 v0 = *(const float4*)(n_lfs + i);
        float4 v1 = *(const float4*)(n_lfs + i + 4);
        h8 o;
        o[0] = (_Float16)v0.x; o[1] = (_Float16)v0.y;
        o[2] = (_Float16)v0.z; o[3] = (_Float16)v0.w;
        o[4] = (_Float16)v1.x; o[5] = (_Float16)v1.y;
        o[6] = (_Float16)v1.z; o[7] = (_Float16)v1.w;
        *(h8*)(n16 + i) = o;
    }
}

// ---------------------------------------------------------------------------
// Kernel 1: K-split GEMM with IN-BLOCK K-reduction (r6).
// grid (16,8,4) = 512 blocks x 4 waves (256 thr) = 2048 waves = 8 waves/CU.
// Wave w of block z handles k-chunk ks = z*4+w (KC=256) over the block's
// 64x64 tile, with the r5-verified per-wave pipeline (own 16KB staging,
// DEPTH=2, steady vmcnt(8), last step vmcnt(0)).
// Epilogue: barrier -> each wave writes acc to its own 64x69 f32 LDS buffer
// (stride 69: 69%32=5, gcd(5,32)=1 -> conflict-free; 4x17664B=69KB reuses
// dead staging) -> barrier -> 256 threads sum 4 partials in f32, pack f16,
// coalesced h8 stores. pg shrinks 16MB -> 4MB (KSG=4), and partial
// summation is f32 in-block (better precision than r5's 16 f16 partials).
// LDS 70656B/block -> 2 blocks/CU = 138KB <= 160KB.
//  XCD swizzle: id=bx+16by+128bz in [0,512); l=(id%8)*64+id/8;
//  z=l>>7 (fixed per XCD-pair), n0=(l&15)*64, m0=((l>>4)&7)*64.
//  Per-XCD ws = 0.5MB A + 2MB B < 4MB L2.
// LDS staging layout + fragment mapping unchanged (verified prior session).
// C/D: col=lane&15, row=quad*4+reg.
// ---------------------------------------------------------------------------
__global__ __launch_bounds__(256) void gemm_lds(
    const unsigned short* __restrict__ vf,    // [B, D] bf16 bits
    const unsigned short* __restrict__ W,     // [E, D] bf16 bits
    _Float16* __restrict__ part)              // [KSG, B, E] f16
{
    // [w*16K, w*16K+8K) = wave w sA (2 x 4KB); +8K = sB (2 x 4KB).
    // Epilogue reuses [0, 70656) as 4 x (64x69 f32) transpose buffers.
    __shared__ __align__(16) char smem[70656];

    const int t = threadIdx.x;
    const int w = t >> 6;        // wave 0..3
    const int L = t & 63;

    const int id = blockIdx.x + 16 * blockIdx.y + 128 * blockIdx.z;
    const int l  = (id & 7) * 64 + (id >> 3);
    const int z  = l >> 7;             // 0..3 global partial slice
    const int n0 = (l & 15) * 64;
    const int m0 = ((l >> 4) & 7) * 64;

    char* stg = smem + w * 16384;      // this wave's staging base

    // ---- staging addresses ----
    const int subrow = L >> 2;                                  // 0..15
    const int qstg = (L & 3) ^ ((L >> 2) & 3) ^ ((L >> 4) & 3); // swizzled k-group
    const int kbeg = (z * 4 + w) * KC;
    const unsigned short* aSrc[4];
    const unsigned short* bSrc[4];
    #pragma unroll
    for (int c = 0; c < 4; ++c) {
        aSrc[c] = vf + (size_t)(m0 + c * 16 + subrow) * D + kbeg + qstg * 8;
        bSrc[c] = W  + (size_t)(n0 + c * 16 + subrow) * D + kbeg + qstg * 8;
    }

    // ---- fragment read offsets ----
    const int r16 = L & 15;
    const int quad = L >> 4;
    const int swz = quad ^ (r16 & 3) ^ ((r16 >> 2) & 3);
    const int aoff = r16 * 64 + swz * 16;   // byte offset within a buffer

    f32x4 acc[4][4] = {};

    auto issue = [&](int step, int buf) {
        const size_t koff = (size_t)step * 32;   // elements
        #pragma unroll
        for (int c = 0; c < 4; ++c) {
            __builtin_amdgcn_global_load_lds(
                (gbl_void*)(aSrc[c] + koff),
                (lds_void*)(stg + buf * 4096 + c * 1024), 16, 0, 0);
            __builtin_amdgcn_global_load_lds(
                (gbl_void*)(bSrc[c] + koff),
                (lds_void*)(stg + 8192 + buf * 4096 + c * 1024), 16, 0, 0);
        }
    };

    issue(0, 0);
    issue(1, 1);

    // waitcnt imm (gfx9): vmcnt split [3:0]+[15:14], exp [6:4], lgkm [11:8].
    //   vmcnt(8)=0x0F78, vmcnt(0)=0x0F70
    #define GSTEP(S, WC, ISS)                                                  \
    {                                                                          \
        const int buf_ = (S) & 1;                                              \
        __builtin_amdgcn_s_waitcnt(WC);                                        \
        bf16x8 af[4], bg[4];                                                   \
        _Pragma("unroll")                                                      \
        for (int i = 0; i < 4; ++i)                                            \
            af[i] = *(const bf16x8*)(stg + buf_ * 4096 + i * 1024 + aoff);     \
        _Pragma("unroll")                                                      \
        for (int j = 0; j < 4; ++j)                                            \
            bg[j] = *(const bf16x8*)(stg + 8192 + buf_ * 4096 + j * 1024 + aoff); \
        _Pragma("unroll")                                                      \
        for (int i = 0; i < 4; ++i)                                            \
            _Pragma("unroll")                                                  \
            for (int j = 0; j < 4; ++j)                                        \
                acc[i][j] = __builtin_amdgcn_mfma_f32_16x16x32_bf16(           \
                    af[i], bg[j], acc[i][j], 0, 0, 0);                         \
        if (ISS) issue((S) + DEPTH, buf_);                                     \
    }

    #pragma unroll 1
    for (int s = 0; s < NSTEP - 1; ++s)
        GSTEP(s, 0x0F78, s + DEPTH < NSTEP);   // steady: vmcnt(8)
    GSTEP(NSTEP - 1, 0x0F70, false);           // vmcnt(0): staging drained
    #undef GSTEP

    // ---- in-block 4-wave reduction + coalesced f16 store ----
    __syncthreads();   // all waves done with staging LDS (vmcnt(0) + lgkm)
    float* ctw = (float*)smem + w * 4416;      // 64x69 f32, conflict-free
    #pragma unroll
    for (int i = 0; i < 4; ++i)
        #pragma unroll
        for (int j = 0; j < 4; ++j)
            #pragma unroll
            for (int r = 0; r < 4; ++r)
                ctw[(i * 16 + quad * 4 + r) * 69 + (j * 16 + r16)] = acc[i][j][r];
    __syncthreads();

    const int row = t >> 2;            // 0..63
    const int cb  = (t & 3) * 16;      // 0,16,32,48
    const float* p0 = (const float*)smem + row * 69 + cb;
    float s[16];
    #pragma unroll
    for (int u = 0; u < 16; ++u)
        s[u] = (p0[u] + p0[4416 + u]) + (p0[8832 + u] + p0[13248 + u]);
    _Float16* po = part + (size_t)z * B * E + (size_t)(m0 + row) * E + n0 + cb;
    h8 v0, v1;
    #pragma unroll
    for (int u = 0; u < 8; ++u) { v0[u] = (_Float16)s[u]; v1[u] = (_Float16)s[u + 8]; }
    *(h8*)po = v0;
    *(h8*)(po + 8) = v1;
}

// ---------------------------------------------------------------------------
// Kernel 2: one block per batch row b (grid = 512):
//   s = sum_ks part[ks][b][:] + bias  -> emb16[b][:] (f16)
//   p_score[b] = -||relu(p_lfs[b] - s)|| -> out[b*513]  (s in full f32)
// ---------------------------------------------------------------------------
__global__ __launch_bounds__(256) void reduce_emb(
    const _Float16* __restrict__ part, const float* __restrict__ bias,
    const float* __restrict__ p_lfs,
    _Float16* __restrict__ emb16, float* __restrict__ out)
{
    const int b = blockIdx.x;
    const int e = threadIdx.x * 4;
    const size_t base = (size_t)b * E + e;
    float4 s = *(const float4*)(bias + e);
    #pragma unroll
    for (int ks = 0; ks < KSG; ++ks) {
        h4 p = *(const h4*)(part + (size_t)ks * B * E + base);
        s.x += (float)p[0]; s.y += (float)p[1];
        s.z += (float)p[2]; s.w += (float)p[3];
    }
    h4 o;
    o[0] = (_Float16)s.x; o[1] = (_Float16)s.y;
    o[2] = (_Float16)s.z; o[3] = (_Float16)s.w;
    *(h4*)(emb16 + base) = o;

    // positive score for row b
    const float4 pl = *(const float4*)(p_lfs + base);
    float d, a = 0.f;
    d = pl.x - s.x; d = fmaxf(d, 0.f); a = fmaf(d, d, a);
    d = pl.y - s.y; d = fmaxf(d, 0.f); a = fmaf(d, d, a);
    d = pl.z - s.z; d = fmaxf(d, 0.f); a = fmaf(d, d, a);
    d = pl.w - s.w; d = fmaxf(d, 0.f); a = fmaf(d, d, a);
    #pragma unroll
    for (int off = 32; off; off >>= 1) a += __shfl_down(a, off, 64);
    __shared__ float red[4];
    if ((threadIdx.x & 63) == 0) red[threadIdx.x >> 6] = a;
    __syncthreads();
    if (threadIdx.x == 0)
        out[(size_t)b * 513] = -sqrtf(red[0] + red[1] + red[2] + red[3]);
}

// ---------------------------------------------------------------------------
// Kernel 3: neg-score partials, f16 math with v_dot2_f32_f16 (f32 accum).
// grid (8,8,8) = 512 blocks. Tile 64(b) x 64(n), 4x4 f32 accs/thread,
// one EC=128 chunk per block. eS stores NEGATED emb so inner loop is
// d = n + (-e) (v_pk_add_f16), relu (v_pk_max_f16), acc = fdot2(d,d,acc).
// pn stored f16 (chunk sums ~128, ulp 0.0625 -> final err ~4e-3 << thr).
// ---------------------------------------------------------------------------
__global__ __launch_bounds__(256, 4) void scores_part(
    const _Float16* __restrict__ emb16,  // [B, E] f16
    const _Float16* __restrict__ n16,    // [N, E] f16
    _Float16* __restrict__ pn)           // [ES, B, N] f16
{
    constexpr int LDH = EC + 8;  // 136 halfs
    __shared__ _Float16 eS[64 * LDH];
    __shared__ _Float16 nS[64 * LDH];

    const int t  = threadIdx.x;
    const int n0 = blockIdx.x * 64;
    const int b0 = blockIdx.y * 64;
    const int e0 = blockIdx.z * EC;

    {
        const int row = t >> 2;            // 0..63
        const int cb  = (t & 3) * 32;      // halfs: 0,32,64,96
        const _Float16* ep = emb16 + (size_t)(b0 + row) * E + e0 + cb;
        const _Float16* np = n16   + (size_t)(n0 + row) * E + e0 + cb;
        _Float16* ed = &eS[row * LDH + cb];
        _Float16* nd = &nS[row * LDH + cb];
        #pragma unroll
        for (int q = 0; q < 4; ++q) {
            h8 v = *(const h8*)(ep + q * 8);
            h8 w = *(const h8*)(np + q * 8);
            *(h8*)(ed + q * 8) = -v;       // pre-negated emb
            *(h8*)(nd + q * 8) = w;
        }
    }
    __syncthreads();

    const int ty = t >> 4;   // 0..15 -> b rows ty+16r
    const int tx = t & 15;   // 0..15 -> n rows tx+16q

    float acc[4][4] = {};
    const h4 z4 = {};

    #pragma unroll 2
    for (int e = 0; e < EC; e += 4) {
        h4 a[4], c[4];
        #pragma unroll
        for (int r = 0; r < 4; ++r)
            a[r] = *(const h4*)&eS[(ty + 16 * r) * LDH + e];
        #pragma unroll
        for (int q = 0; q < 4; ++q)
            c[q] = *(const h4*)&nS[(tx + 16 * q) * LDH + e];
        #pragma unroll
        for (int r = 0; r < 4; ++r)
            #pragma unroll
            for (int q = 0; q < 4; ++q) {
                h4 d = c[q] + a[r];                       // n - e
                d = __builtin_elementwise_max(d, z4);     // relu
                h2 dl = __builtin_shufflevector(d, d, 0, 1);
                h2 dh = __builtin_shufflevector(d, d, 2, 3);
                acc[r][q] = fdot2(dl, dl, acc[r][q]);
                acc[r][q] = fdot2(dh, dh, acc[r][q]);
            }
    }

    _Float16* po = pn + (size_t)blockIdx.z * B * N;
    #pragma unroll
    for (int r = 0; r < 4; ++r) {
        const size_t ob = (size_t)(b0 + ty + 16 * r) * N;
        #pragma unroll
        for (int q = 0; q < 4; ++q)
            po[ob + n0 + tx + 16 * q] = (_Float16)acc[r][q];
    }
}

// ---------------------------------------------------------------------------
// Kernel 4: negative-score reduce over ES parts (positives done in K2).
// ---------------------------------------------------------------------------
__global__ __launch_bounds__(256) void scores_final(
    const _Float16* __restrict__ pn,  // [ES, B, N] f16
    float* __restrict__ out)          // [B, 1+N]
{
    const int i = blockIdx.x * 256 + threadIdx.x;   // 0..B*N-1
    const int b = i >> 9;                           // /N
    const int n = i & (N - 1);
    float s = 0.f;
    #pragma unroll
    for (int z = 0; z < ES; ++z)
        s += (float)pn[(size_t)z * B * N + i];
    out[(size_t)b * 513 + 1 + n] = -sqrtf(s);
}

extern "C" void kernel_launch(void* const* d_in, const int* in_sizes, int n_in,
                              void* d_out, int out_size, void* d_ws, size_t ws_size,
                              hipStream_t stream) {
    const float* vf    = (const float*)d_in[0];  // [512,4096] f32
    const float* p_lfs = (const float*)d_in[1];  // [512,1024] f32
    const float* n_lfs = (const float*)d_in[2];  // [512,1024] f32
    const float* W     = (const float*)d_in[3];  // [1024,4096] f32
    const float* bias  = (const float*)d_in[4];  // [1024] f32
    float* out = (float*)d_out;                  // [512,513] f32

    // ws layout (22 MB peak):
    //   [0,  4MB): pg    f16 [KSG=4,512,1024]
    //   [4,  8MB): pn    f16 [ES=8,512,512]
    //   [8, 12MB): vfB   bf16 [512,4096]
    //   [12,20MB): WB    bf16 [1024,4096]
    //   [20,21MB): emb16 f16 [512,1024]
    //   [21,22MB): n16   f16 [512,1024]
    char* ws = (char*)d_ws;
    _Float16*       pg    = (_Float16*)ws;
    _Float16*       pn    = (_Float16*)(ws + ((size_t)4 << 20));
    unsigned short* vfB   = (unsigned short*)(ws + ((size_t)8 << 20));
    unsigned short* WB    = (unsigned short*)(ws + ((size_t)12 << 20));
    _Float16*       emb16 = (_Float16*)(ws + ((size_t)20 << 20));
    _Float16*       n16   = (_Float16*)(ws + ((size_t)21 << 20));

    cvt_all<<<3328, 256, 0, stream>>>(vf, W, n_lfs, vfB, WB, n16);

    dim3 g1(E / 64, B / 64, KSG);  // (16, 8, 4) = 512 four-wave blocks
    gemm_lds<<<g1, 256, 0, stream>>>(vfB, WB, pg);

    reduce_emb<<<B, 256, 0, stream>>>(pg, bias, p_lfs, emb16, out);

    dim3 g3(N / 64, B / 64, ES);   // (8, 8, 8) = 512 blocks
    scores_part<<<g3, 256, 0, stream>>>(emb16, n16, pn);

    scores_final<<<(B * N) / 256, 256, 0, stream>>>(pn, out);
}